// Round 11
// baseline (658.971 us; speedup 1.0000x reference)
//
#include <hip/hip_runtime.h>
#include <hip/hip_bf16.h>

#define NN 100000
#define NE 1600000
#define DIN 128
#define NG 512
#define MAXD 64
#define NBUK 391               // dst>>8 buckets (256 nodes each)
#define BCAP 5120              // mean 4092, +16 sigma
#define CHUNK ((NE + NBUK - 1) / NBUK)

// ============ fused: phase-1 binning (blocks 0..NBUK) || input GEMM (rest) ============
// input GEMM: float2-packed W0 in LDS (ds_read_b64), 2 nodes/wave, 4 fmaf chains
#define GB 512
__global__ void __launch_bounds__(512) k_front(const int* __restrict__ src,
                                               const int* __restrict__ dst,
                                               int* __restrict__ cursor,
                                               unsigned int* __restrict__ bucket,
                                               const float* __restrict__ x,
                                               const float* __restrict__ W0,
                                               const float* __restrict__ b0,
                                               float* __restrict__ h) {
    __shared__ float2 sW2[64 * 64];          // 32 KB
    __shared__ int lcnt[NBUK];
    __shared__ int lbase[NBUK];
    if (blockIdx.x < NBUK) {
        // ---- bin edges by dst>>8 via LDS histogram; 1 global atomic per (block,bucket) ----
        for (int i = threadIdx.x; i < NBUK; i += 512) lcnt[i] = 0;
        __syncthreads();
        int e0 = blockIdx.x * CHUNK;
        int e1 = min(e0 + CHUNK, NE);
        for (int e = e0 + (int)threadIdx.x; e < e1; e += 512)
            atomicAdd(&lcnt[dst[e] >> 8], 1);
        __syncthreads();
        for (int i = threadIdx.x; i < NBUK; i += 512) {
            int c = lcnt[i];
            lbase[i] = c ? atomicAdd(&cursor[i], c) : 0;
            lcnt[i] = 0;
        }
        __syncthreads();
        for (int e = e0 + (int)threadIdx.x; e < e1; e += 512) {
            int d = dst[e];
            int s = src[e];
            int bk = d >> 8;
            int pos = lbase[bk] + atomicAdd(&lcnt[bk], 1);
            if (pos < BCAP)
                bucket[(size_t)bk * BCAP + pos] = ((unsigned)s << 8) | (unsigned)(d & 255);
        }
    } else {
        // ---- input GEMM: h = relu(x @ W0 + b0) ----
        for (int i = threadIdx.x; i < 64 * 64; i += 512) {
            int k2 = i >> 6, j = i & 63;
            sW2[i] = make_float2(W0[(2 * k2) * 64 + j], W0[(2 * k2 + 1) * 64 + j]);
        }
        __syncthreads();
        int lane = threadIdx.x & 63;
        int wv   = __builtin_amdgcn_readfirstlane(
                       (int)(((blockIdx.x - NBUK) * 512 + threadIdx.x) >> 6));
        int nw   = (GB * 512) >> 6;
        float bj = b0[lane];
        for (int p = wv; p < NN / 2; p += nw) {
            int n0 = 2 * p, n1 = n0 + 1;
            const float* x0 = x + (size_t)n0 * DIN;   // wave-uniform -> s_load
            const float* x1 = x + (size_t)n1 * DIN;
            float a0 = bj, c0 = 0.0f, a1 = bj, c1 = 0.0f;
#pragma unroll 16
            for (int k2 = 0; k2 < 64; ++k2) {
                float2 w = sW2[k2 * 64 + lane];
                a0 = fmaf(x0[2 * k2],     w.x, a0);
                c0 = fmaf(x0[2 * k2 + 1], w.y, c0);
                a1 = fmaf(x1[2 * k2],     w.x, a1);
                c1 = fmaf(x1[2 * k2 + 1], w.y, c1);
            }
            h[(size_t)n0 * 64 + lane] = fmaxf(a0 + c0, 0.0f);
            h[(size_t)n1 * 64 + lane] = fmaxf(a1 + c1, 0.0f);
        }
    }
}

// ---- gemmLR body: g(bf16) = h@Wl ; r(fp32,in-place) = h@Wr + bl ----
__device__ __forceinline__ void gemmLR_body(float2* sW, int tid, int nblk, int bidx,
                                            float* __restrict__ h_r,
                                            __hip_bfloat16* __restrict__ g,
                                            const float* __restrict__ Wl,
                                            const float* __restrict__ bl,
                                            const float* __restrict__ Wr) {
    for (int i = tid; i < 64 * 64; i += 256)
        sW[i] = make_float2(Wl[i], Wr[i]);
    __syncthreads();
    int lane = tid & 63;
    float bj = bl[lane];
    int wv = __builtin_amdgcn_readfirstlane((int)((bidx * 256 + tid) >> 6));
    int nw = nblk * 4;
    for (int q = wv; q < NN / 4; q += nw) {
        const float* hp = h_r + (size_t)(4 * q) * 64;   // wave-uniform -> s_load
        float l0 = 0, l1 = 0, l2 = 0, l3 = 0;
        float r0 = 0, r1 = 0, r2 = 0, r3 = 0;
#pragma unroll 16
        for (int k = 0; k < 64; ++k) {
            float2 w = sW[k * 64 + lane];
            float s0 = hp[k], s1 = hp[64 + k], s2 = hp[128 + k], s3 = hp[192 + k];
            l0 = fmaf(s0, w.x, l0); r0 = fmaf(s0, w.y, r0);
            l1 = fmaf(s1, w.x, l1); r1 = fmaf(s1, w.y, r1);
            l2 = fmaf(s2, w.x, l2); r2 = fmaf(s2, w.y, r2);
            l3 = fmaf(s3, w.x, l3); r3 = fmaf(s3, w.y, r3);
        }
        size_t base = (size_t)(4 * q) * 64 + lane;
        g[base]       = __float2bfloat16(l0);  h_r[base]       = r0 + bj;
        g[base + 64]  = __float2bfloat16(l1);  h_r[base + 64]  = r1 + bj;
        g[base + 128] = __float2bfloat16(l2);  h_r[base + 128] = r2 + bj;
        g[base + 192] = __float2bfloat16(l3);  h_r[base + 192] = r3 + bj;
    }
}

// ============ fused: phase-2 ELL build (blocks 0..NBUK) || gemmLR layer 0 ============
#define MGB 1024
__global__ void __launch_bounds__(256) k_mid(const unsigned int* __restrict__ bucket,
                                             const int* __restrict__ cursor,
                                             int* __restrict__ cnt,
                                             int* __restrict__ ell,
                                             float* __restrict__ h_r,
                                             __hip_bfloat16* __restrict__ g,
                                             const float* __restrict__ Wl,
                                             const float* __restrict__ bl,
                                             const float* __restrict__ Wr) {
    __shared__ float2 sW[64 * 64];
    __shared__ int lc[256];
    if (blockIdx.x < NBUK) {
        lc[threadIdx.x] = 0;
        int b = blockIdx.x;
        int4* ep = (int4*)(ell + (((size_t)b << 8) * MAXD));
        for (int i = threadIdx.x; i < (256 * MAXD) / 4; i += 256)
            ep[i] = make_int4(NN, NN, NN, NN);          // sentinel -> zero row of G
        __syncthreads();
        int m = min(cursor[b], BCAP);
        const unsigned int* bp = bucket + (size_t)b * BCAP;
        for (int i = threadIdx.x; i < m; i += 256) {
            unsigned v = bp[i];
            int dlo = (int)(v & 255u);
            int s   = (int)(v >> 8);
            int p   = atomicAdd(&lc[dlo], 1);           // LDS atomic
            if (p < MAXD)
                ell[(((size_t)b << 8) + dlo) * MAXD + p] = s;
        }
        __syncthreads();
        int n = (b << 8) + (int)threadIdx.x;
        if (n < NN) cnt[n] = lc[threadIdx.x];
    } else {
        gemmLR_body(sW, threadIdx.x, MGB, blockIdx.x - NBUK, h_r, g, Wl, bl, Wr);
    }
}

// ============ standalone gemmLR (layers 1,2) ============
__global__ void __launch_bounds__(256) k_gemmLR(float* __restrict__ h_r,
                                                __hip_bfloat16* __restrict__ g,
                                                const float* __restrict__ Wl,
                                                const float* __restrict__ bl,
                                                const float* __restrict__ Wr) {
    __shared__ float2 sW[64 * 64];
    gemmLR_body(sW, threadIdx.x, gridDim.x, blockIdx.x, h_r, g, Wl, bl, Wr);
}

// ============ gather: 4 nodes/wave, 8 B/lane (bf16x4), sentinel-padded ============
// quarter q = lane>>4 owns node 4t+q; lane owns features [4*qcol .. 4*qcol+3].
__global__ void __launch_bounds__(256) k_gather(const uint2* __restrict__ g4,
                                                float* __restrict__ r_h,
                                                const int* __restrict__ cnt,
                                                const int* __restrict__ ell) {
    int lane = threadIdx.x & 63;
    int qcol = lane & 15;
    int qb   = lane & 48;                    // quarter base lane
    int wv = __builtin_amdgcn_readfirstlane((int)((blockIdx.x * 256 + threadIdx.x) >> 6));
    int nw = (gridDim.x * 256) >> 6;
    for (int t = wv; t < NN / 4; t += nw) {
        int nb = 4 * t;
        int d0 = cnt[nb], d1 = cnt[nb + 1], d2 = cnt[nb + 2], d3 = cnt[nb + 3]; // s_load
        int q    = lane >> 4;
        int myn  = nb + q;
        int mydg = (q == 0) ? d0 : (q == 1) ? d1 : (q == 2) ? d2 : d3;
        int maxd = min(max(max(d0, d1), max(d2, d3)), MAXD);
        int iters = (maxd + 7) & ~7;                    // mult of 8; sentinels add 0
        float4 rv = ((const float4*)r_h)[(size_t)myn * 16 + qcol];  // hoisted
        const int* ep = ell + (size_t)myn * MAXD;
        int ix0 = ep[qcol];
        int ix1 = (iters > 16) ? ep[16 + qcol] : NN;
        int ix2 = (iters > 32) ? ep[32 + qcol] : NN;
        int ix3 = (iters > 48) ? ep[48 + qcol] : NN;
        float A0=0,A1=0,A2=0,A3=0;
        float B0=0,B1=0,B2=0,B3=0;
        float C0=0,C1=0,C2=0,C3=0;
        float D0=0,D1=0,D2=0,D3=0;
        auto lo = [](unsigned u) { return __uint_as_float(u << 16); };
        auto hi = [](unsigned u) { return __uint_as_float(u & 0xffff0000u); };
        auto chunkAcc = [&](int ixC, int jlim) {
            for (int j = 0; j < jlim; j += 4) {
                int s0 = __shfl(ixC, qb + j);
                int s1 = __shfl(ixC, qb + j + 1);
                int s2 = __shfl(ixC, qb + j + 2);
                int s3 = __shfl(ixC, qb + j + 3);
                uint2 u0 = g4[(size_t)s0 * 16 + qcol];
                uint2 u1 = g4[(size_t)s1 * 16 + qcol];
                uint2 u2 = g4[(size_t)s2 * 16 + qcol];
                uint2 u3 = g4[(size_t)s3 * 16 + qcol];
                A0 += lo(u0.x); A1 += hi(u0.x); A2 += lo(u0.y); A3 += hi(u0.y);
                B0 += lo(u1.x); B1 += hi(u1.x); B2 += lo(u1.y); B3 += hi(u1.y);
                C0 += lo(u2.x); C1 += hi(u2.x); C2 += lo(u2.y); C3 += hi(u2.y);
                D0 += lo(u3.x); D1 += hi(u3.x); D2 += lo(u3.y); D3 += hi(u3.y);
            }
        };
        chunkAcc(ix0, min(iters, 16));
        if (iters > 16) chunkAcc(ix1, min(iters - 16, 16));
        if (iters > 32) chunkAcc(ix2, min(iters - 32, 16));
        if (iters > 48) chunkAcc(ix3, min(iters - 48, 16));
        float inv = 1.0f / fmaxf((float)mydg, 1.0f);
        float s0 = (A0 + B0) + (C0 + D0);
        float s1 = (A1 + B1) + (C1 + D1);
        float s2 = (A2 + B2) + (C2 + D2);
        float s3 = (A3 + B3) + (C3 + D3);
        rv.x = fmaxf(fmaf(s0, inv, rv.x), 0.0f);
        rv.y = fmaxf(fmaf(s1, inv, rv.y), 0.0f);
        rv.z = fmaxf(fmaf(s2, inv, rv.z), 0.0f);
        rv.w = fmaxf(fmaf(s3, inv, rv.w), 0.0f);
        ((float4*)r_h)[(size_t)myn * 16 + qcol] = rv;
    }
}

// ============ pooling + output GEMM (last-block-does-out) ============
__global__ void __launch_bounds__(256) k_pool_out(const int* __restrict__ batch,
                                                  const float* __restrict__ h,
                                                  float* __restrict__ pool,
                                                  float* __restrict__ cntg,
                                                  int* __restrict__ done,
                                                  const float* __restrict__ W1,
                                                  const float* __restrict__ b1,
                                                  float* __restrict__ out) {
    __shared__ float sW[64 * 64];
    __shared__ float srow[4][64];
    __shared__ int lastFlag;
    int lane = threadIdx.x & 63;
    int wid  = (blockIdx.x * 256 + threadIdx.x) >> 6;
    int nw   = (gridDim.x * 256) >> 6;
    int chunk = (NN + nw - 1) / nw;
    int n0 = wid * chunk;
    if (n0 < NN) {
        int n1 = min(n0 + chunk, NN);
        int cur = batch[n0];
        float acc = 0.0f, acc_c = 0.0f;
        for (int n = n0; n < n1; ++n) {
            int b = batch[n];
            if (b != cur) {
                atomicAdd(&pool[(size_t)cur * 64 + lane], acc);
                if (lane == 0) atomicAdd(&cntg[cur], acc_c);
                acc = 0.0f; acc_c = 0.0f; cur = b;
            }
            acc   += h[(size_t)n * 64 + lane];
            acc_c += 1.0f;
        }
        atomicAdd(&pool[(size_t)cur * 64 + lane], acc);
        if (lane == 0) atomicAdd(&cntg[cur], acc_c);
    }
    __threadfence();
    __syncthreads();
    if (threadIdx.x == 0)
        lastFlag = (atomicAdd(done, 1) == (int)gridDim.x - 1) ? 1 : 0;
    __syncthreads();
    if (!lastFlag) return;
    __threadfence();
    // ---- final GEMM in the last block; pool/cntg via atomic loads (coherent) ----
    for (int i = threadIdx.x; i < 64 * 64; i += 256) sW[i] = W1[i];
    __syncthreads();
    int lw = threadIdx.x >> 6;
    float bj = b1[lane];
    for (int gidx = lw; gidx < NG; gidx += 4) {
        float pv = atomicAdd(&pool[(size_t)gidx * 64 + lane], 0.0f);  // atomic load
        srow[lw][lane] = pv;
        float c0 = 0.0f;
        if (lane == 0) c0 = atomicAdd(&cntg[gidx], 0.0f);
        c0 = __shfl(c0, 0);
        __builtin_amdgcn_wave_barrier();
        float ic = 1.0f / fmaxf(c0, 1.0f);
        float acc = 0.0f;
#pragma unroll
        for (int k = 0; k < 64; ++k)
            acc = fmaf(srow[lw][k], sW[k * 64 + lane], acc);
        out[(size_t)gidx * 64 + lane] = fmaf(acc, ic, bj);
        __builtin_amdgcn_wave_barrier();
    }
}

extern "C" void kernel_launch(void* const* d_in, const int* in_sizes, int n_in,
                              void* d_out, int out_size, void* d_ws, size_t ws_size,
                              hipStream_t stream) {
    const float* x     = (const float*)d_in[0];
    const int*   ei    = (const int*)d_in[1];   // [2,E]
    const int*   batch = (const int*)d_in[3];
    const float* W0    = (const float*)d_in[4];
    const float* b0    = (const float*)d_in[5];
    const float* Wl    = (const float*)d_in[6];
    const float* bl    = (const float*)d_in[7];
    const float* Wr    = (const float*)d_in[8];
    const float* W1    = (const float*)d_in[9];
    const float* b1    = (const float*)d_in[10];
    float* out = (float*)d_out;

    char* ws = (char*)d_ws;
    size_t off = 0;
    auto alloc = [&](size_t bytes) -> void* {
        void* p = ws + off;
        off += (bytes + 255) & ~(size_t)255;
        return p;
    };
    float*          A      = (float*)alloc((size_t)NN * 64 * 4);          // h / r / h'
    __hip_bfloat16* G      = (__hip_bfloat16*)alloc((size_t)NN * 64 * 2); // g (bf16), NN rows
    // zero region starts EXACTLY at G's row NN (sentinel zero row), then cursor/pool/cntg/done
    size_t zstart = off;
    (void)alloc((size_t)MAXD * 2);                                        // G zero row (128 B)
    int*   cursor = (int*)alloc((size_t)NBUK * 4);
    float* pool   = (float*)alloc((size_t)NG * 64 * 4);
    float* cntg   = (float*)alloc((size_t)NG * 4);
    int*   done   = (int*)alloc((size_t)4);
    size_t zlen = off - zstart;
    int*          ell    = (int*)alloc((size_t)NBUK * 256 * MAXD * 4);    // padded ELL
    unsigned int* bucket = (unsigned int*)alloc((size_t)NBUK * BCAP * 4);
    int*          cnt    = (int*)alloc((size_t)NN * 4);                   // fully written

    const int* src = ei;
    const int* dst = ei + NE;

    hipMemsetAsync(ws + zstart, 0, zlen, stream);

    // phase-1 binning || input projection
    k_front<<<NBUK + GB, 512, 0, stream>>>(src, dst, cursor, bucket, x, W0, b0, A);
    // phase-2 ELL build || gemmLR layer 0
    k_mid<<<NBUK + MGB, 256, 0, stream>>>(bucket, cursor, cnt, ell, A, G,
                                          Wl, bl, Wr);
    k_gather<<<2048, 256, 0, stream>>>((const uint2*)G, A, cnt, ell);

    for (int l = 1; l < 3; ++l) {
        k_gemmLR<<<1024, 256, 0, stream>>>(A, G,
                                           Wl + (size_t)l * 64 * 64,
                                           bl + (size_t)l * 64,
                                           Wr + (size_t)l * 64 * 64);
        k_gather<<<2048, 256, 0, stream>>>((const uint2*)G, A, cnt, ell);
    }

    k_pool_out<<<256, 256, 0, stream>>>(batch, A, pool, cntg, done, W1, b1, out);
}

// Round 12
// 521.252 us; speedup vs baseline: 1.2642x; 1.2642x over previous
//
#include <hip/hip_runtime.h>
#include <hip/hip_bf16.h>

#define NN 100000
#define NE 1600000
#define DIN 128
#define NG 512
#define MAXD 64
#define NBUK 391               // dst>>8 buckets (256 nodes each)
#define BCAP 5120              // mean 4092, +16 sigma
#define CHUNK ((NE + NBUK - 1) / NBUK)

// ============ fused: phase-1 binning (blocks 0..NBUK) || input GEMM (rest) ============
// input GEMM: float2-packed W0 in LDS (ds_read_b64), 2 nodes/wave, 4 fmaf chains
#define GB 512
__global__ void __launch_bounds__(512) k_front(const int* __restrict__ src,
                                               const int* __restrict__ dst,
                                               int* __restrict__ cursor,
                                               unsigned int* __restrict__ bucket,
                                               const float* __restrict__ x,
                                               const float* __restrict__ W0,
                                               const float* __restrict__ b0,
                                               float* __restrict__ h) {
    __shared__ float2 sW2[64 * 64];          // 32 KB
    __shared__ int lcnt[NBUK];
    __shared__ int lbase[NBUK];
    if (blockIdx.x < NBUK) {
        // ---- bin edges by dst>>8 via LDS histogram; 1 global atomic per (block,bucket) ----
        for (int i = threadIdx.x; i < NBUK; i += 512) lcnt[i] = 0;
        __syncthreads();
        int e0 = blockIdx.x * CHUNK;
        int e1 = min(e0 + CHUNK, NE);
        for (int e = e0 + (int)threadIdx.x; e < e1; e += 512)
            atomicAdd(&lcnt[dst[e] >> 8], 1);
        __syncthreads();
        for (int i = threadIdx.x; i < NBUK; i += 512) {
            int c = lcnt[i];
            lbase[i] = c ? atomicAdd(&cursor[i], c) : 0;
            lcnt[i] = 0;
        }
        __syncthreads();
        for (int e = e0 + (int)threadIdx.x; e < e1; e += 512) {
            int d = dst[e];
            int s = src[e];
            int bk = d >> 8;
            int pos = lbase[bk] + atomicAdd(&lcnt[bk], 1);
            if (pos < BCAP)
                bucket[(size_t)bk * BCAP + pos] = ((unsigned)s << 8) | (unsigned)(d & 255);
        }
    } else {
        // ---- input GEMM: h = relu(x @ W0 + b0) ----
        for (int i = threadIdx.x; i < 64 * 64; i += 512) {
            int k2 = i >> 6, j = i & 63;
            sW2[i] = make_float2(W0[(2 * k2) * 64 + j], W0[(2 * k2 + 1) * 64 + j]);
        }
        __syncthreads();
        int lane = threadIdx.x & 63;
        int wv   = __builtin_amdgcn_readfirstlane(
                       (int)(((blockIdx.x - NBUK) * 512 + threadIdx.x) >> 6));
        int nw   = (GB * 512) >> 6;
        float bj = b0[lane];
        for (int p = wv; p < NN / 2; p += nw) {
            int n0 = 2 * p, n1 = n0 + 1;
            const float* x0 = x + (size_t)n0 * DIN;   // wave-uniform -> s_load
            const float* x1 = x + (size_t)n1 * DIN;
            float a0 = bj, c0 = 0.0f, a1 = bj, c1 = 0.0f;
#pragma unroll 16
            for (int k2 = 0; k2 < 64; ++k2) {
                float2 w = sW2[k2 * 64 + lane];
                a0 = fmaf(x0[2 * k2],     w.x, a0);
                c0 = fmaf(x0[2 * k2 + 1], w.y, c0);
                a1 = fmaf(x1[2 * k2],     w.x, a1);
                c1 = fmaf(x1[2 * k2 + 1], w.y, c1);
            }
            h[(size_t)n0 * 64 + lane] = fmaxf(a0 + c0, 0.0f);
            h[(size_t)n1 * 64 + lane] = fmaxf(a1 + c1, 0.0f);
        }
    }
}

// ---- gemmLR body: g(bf16) = h@Wl ; r(fp32,in-place) = h@Wr + bl ----
__device__ __forceinline__ void gemmLR_body(float2* sW, int tid, int nblk, int bidx,
                                            float* __restrict__ h_r,
                                            __hip_bfloat16* __restrict__ g,
                                            const float* __restrict__ Wl,
                                            const float* __restrict__ bl,
                                            const float* __restrict__ Wr) {
    for (int i = tid; i < 64 * 64; i += 256)
        sW[i] = make_float2(Wl[i], Wr[i]);
    __syncthreads();
    int lane = tid & 63;
    float bj = bl[lane];
    int wv = __builtin_amdgcn_readfirstlane((int)((bidx * 256 + tid) >> 6));
    int nw = nblk * 4;
    for (int q = wv; q < NN / 4; q += nw) {
        const float* hp = h_r + (size_t)(4 * q) * 64;   // wave-uniform -> s_load
        float l0 = 0, l1 = 0, l2 = 0, l3 = 0;
        float r0 = 0, r1 = 0, r2 = 0, r3 = 0;
#pragma unroll 16
        for (int k = 0; k < 64; ++k) {
            float2 w = sW[k * 64 + lane];
            float s0 = hp[k], s1 = hp[64 + k], s2 = hp[128 + k], s3 = hp[192 + k];
            l0 = fmaf(s0, w.x, l0); r0 = fmaf(s0, w.y, r0);
            l1 = fmaf(s1, w.x, l1); r1 = fmaf(s1, w.y, r1);
            l2 = fmaf(s2, w.x, l2); r2 = fmaf(s2, w.y, r2);
            l3 = fmaf(s3, w.x, l3); r3 = fmaf(s3, w.y, r3);
        }
        size_t base = (size_t)(4 * q) * 64 + lane;
        g[base]       = __float2bfloat16(l0);  h_r[base]       = r0 + bj;
        g[base + 64]  = __float2bfloat16(l1);  h_r[base + 64]  = r1 + bj;
        g[base + 128] = __float2bfloat16(l2);  h_r[base + 128] = r2 + bj;
        g[base + 192] = __float2bfloat16(l3);  h_r[base + 192] = r3 + bj;
    }
}

// ============ fused: phase-2 ELL build (blocks 0..NBUK) || gemmLR layer 0 ============
#define MGB 1024
__global__ void __launch_bounds__(256) k_mid(const unsigned int* __restrict__ bucket,
                                             const int* __restrict__ cursor,
                                             int* __restrict__ cnt,
                                             int* __restrict__ ell,
                                             float* __restrict__ h_r,
                                             __hip_bfloat16* __restrict__ g,
                                             const float* __restrict__ Wl,
                                             const float* __restrict__ bl,
                                             const float* __restrict__ Wr) {
    __shared__ float2 sW[64 * 64];
    __shared__ int lc[256];
    if (blockIdx.x < NBUK) {
        lc[threadIdx.x] = 0;
        int b = blockIdx.x;
        int4* ep = (int4*)(ell + (((size_t)b << 8) * MAXD));
        for (int i = threadIdx.x; i < (256 * MAXD) / 4; i += 256)
            ep[i] = make_int4(NN, NN, NN, NN);          // sentinel -> zero row of G
        __syncthreads();
        int m = min(cursor[b], BCAP);
        const unsigned int* bp = bucket + (size_t)b * BCAP;
        for (int i = threadIdx.x; i < m; i += 256) {
            unsigned v = bp[i];
            int dlo = (int)(v & 255u);
            int s   = (int)(v >> 8);
            int p   = atomicAdd(&lc[dlo], 1);           // LDS atomic
            if (p < MAXD)
                ell[(((size_t)b << 8) + dlo) * MAXD + p] = s;
        }
        __syncthreads();
        int n = (b << 8) + (int)threadIdx.x;
        if (n < NN) cnt[n] = lc[threadIdx.x];
    } else {
        gemmLR_body(sW, threadIdx.x, MGB, blockIdx.x - NBUK, h_r, g, Wl, bl, Wr);
    }
}

// ============ standalone gemmLR (layers 1,2) ============
__global__ void __launch_bounds__(256) k_gemmLR(float* __restrict__ h_r,
                                                __hip_bfloat16* __restrict__ g,
                                                const float* __restrict__ Wl,
                                                const float* __restrict__ bl,
                                                const float* __restrict__ Wr) {
    __shared__ float2 sW[64 * 64];
    gemmLR_body(sW, threadIdx.x, gridDim.x, blockIdx.x, h_r, g, Wl, bl, Wr);
}

// ============ gather: 4 nodes/wave, 8 B/lane (bf16x4), sentinel-padded ============
// quarter q = lane>>4 owns node 4t+q; lane owns features [4*qcol .. 4*qcol+3].
__global__ void __launch_bounds__(256) k_gather(const uint2* __restrict__ g4,
                                                float* __restrict__ r_h,
                                                const int* __restrict__ cnt,
                                                const int* __restrict__ ell) {
    int lane = threadIdx.x & 63;
    int qcol = lane & 15;
    int qb   = lane & 48;                    // quarter base lane
    int wv = __builtin_amdgcn_readfirstlane((int)((blockIdx.x * 256 + threadIdx.x) >> 6));
    int nw = (gridDim.x * 256) >> 6;
    for (int t = wv; t < NN / 4; t += nw) {
        int nb = 4 * t;
        int d0 = cnt[nb], d1 = cnt[nb + 1], d2 = cnt[nb + 2], d3 = cnt[nb + 3]; // s_load
        int q    = lane >> 4;
        int myn  = nb + q;
        int mydg = (q == 0) ? d0 : (q == 1) ? d1 : (q == 2) ? d2 : d3;
        int maxd = min(max(max(d0, d1), max(d2, d3)), MAXD);
        int iters = (maxd + 7) & ~7;                    // mult of 8; sentinels add 0
        float4 rv = ((const float4*)r_h)[(size_t)myn * 16 + qcol];  // hoisted
        const int* ep = ell + (size_t)myn * MAXD;
        int ix0 = ep[qcol];
        int ix1 = (iters > 16) ? ep[16 + qcol] : NN;
        int ix2 = (iters > 32) ? ep[32 + qcol] : NN;
        int ix3 = (iters > 48) ? ep[48 + qcol] : NN;
        float A0=0,A1=0,A2=0,A3=0;
        float B0=0,B1=0,B2=0,B3=0;
        float C0=0,C1=0,C2=0,C3=0;
        float D0=0,D1=0,D2=0,D3=0;
        auto lo = [](unsigned u) { return __uint_as_float(u << 16); };
        auto hi = [](unsigned u) { return __uint_as_float(u & 0xffff0000u); };
        auto chunkAcc = [&](int ixC, int jlim) {
            for (int j = 0; j < jlim; j += 4) {
                int s0 = __shfl(ixC, qb + j);
                int s1 = __shfl(ixC, qb + j + 1);
                int s2 = __shfl(ixC, qb + j + 2);
                int s3 = __shfl(ixC, qb + j + 3);
                uint2 u0 = g4[(size_t)s0 * 16 + qcol];
                uint2 u1 = g4[(size_t)s1 * 16 + qcol];
                uint2 u2 = g4[(size_t)s2 * 16 + qcol];
                uint2 u3 = g4[(size_t)s3 * 16 + qcol];
                A0 += lo(u0.x); A1 += hi(u0.x); A2 += lo(u0.y); A3 += hi(u0.y);
                B0 += lo(u1.x); B1 += hi(u1.x); B2 += lo(u1.y); B3 += hi(u1.y);
                C0 += lo(u2.x); C1 += hi(u2.x); C2 += lo(u2.y); C3 += hi(u2.y);
                D0 += lo(u3.x); D1 += hi(u3.x); D2 += lo(u3.y); D3 += hi(u3.y);
            }
        };
        chunkAcc(ix0, min(iters, 16));
        if (iters > 16) chunkAcc(ix1, min(iters - 16, 16));
        if (iters > 32) chunkAcc(ix2, min(iters - 32, 16));
        if (iters > 48) chunkAcc(ix3, min(iters - 48, 16));
        float inv = 1.0f / fmaxf((float)mydg, 1.0f);
        float s0 = (A0 + B0) + (C0 + D0);
        float s1 = (A1 + B1) + (C1 + D1);
        float s2 = (A2 + B2) + (C2 + D2);
        float s3 = (A3 + B3) + (C3 + D3);
        rv.x = fmaxf(fmaf(s0, inv, rv.x), 0.0f);
        rv.y = fmaxf(fmaf(s1, inv, rv.y), 0.0f);
        rv.z = fmaxf(fmaf(s2, inv, rv.z), 0.0f);
        rv.w = fmaxf(fmaf(s3, inv, rv.w), 0.0f);
        ((float4*)r_h)[(size_t)myn * 16 + qcol] = rv;
    }
}

// ============ pooling (batch sorted -> run accumulate) ============
__global__ void __launch_bounds__(256) k_pool(const int* __restrict__ batch,
                                              const float* __restrict__ h,
                                              float* __restrict__ pool,
                                              float* __restrict__ cntg) {
    int lane = threadIdx.x & 63;
    int wid  = (blockIdx.x * 256 + threadIdx.x) >> 6;
    int nw   = (gridDim.x * 256) >> 6;
    int chunk = (NN + nw - 1) / nw;
    int n0 = wid * chunk;
    if (n0 >= NN) return;
    int n1 = min(n0 + chunk, NN);
    int cur = batch[n0];
    float acc = 0.0f, acc_c = 0.0f;
    for (int n = n0; n < n1; ++n) {
        int b = batch[n];
        if (b != cur) {
            atomicAdd(&pool[(size_t)cur * 64 + lane], acc);
            if (lane == 0) atomicAdd(&cntg[cur], acc_c);
            acc = 0.0f; acc_c = 0.0f; cur = b;
        }
        acc   += h[(size_t)n * 64 + lane];
        acc_c += 1.0f;
    }
    atomicAdd(&pool[(size_t)cur * 64 + lane], acc);
    if (lane == 0) atomicAdd(&cntg[cur], acc_c);
}

// ============ output GEMM ============
__global__ void __launch_bounds__(256) k_out(const float* __restrict__ pool,
                                             const float* __restrict__ cntg,
                                             const float* __restrict__ W1,
                                             const float* __restrict__ b1,
                                             float* __restrict__ out) {
    __shared__ float sW[64 * 64];
    for (int i = threadIdx.x; i < 64 * 64; i += 256) sW[i] = W1[i];
    __syncthreads();
    int lane = threadIdx.x & 63;
    int wid  = (blockIdx.x * 256 + threadIdx.x) >> 6;
    int nw   = (gridDim.x * 256) >> 6;
    for (int gidx = wid; gidx < NG; gidx += nw) {
        float ic = 1.0f / fmaxf(cntg[gidx], 1.0f);
        float acc = 0.0f;
#pragma unroll
        for (int k = 0; k < 64; ++k)
            acc = fmaf(pool[(size_t)gidx * 64 + k], sW[k * 64 + lane], acc);
        out[(size_t)gidx * 64 + lane] = fmaf(acc, ic, b1[lane]);
    }
}

extern "C" void kernel_launch(void* const* d_in, const int* in_sizes, int n_in,
                              void* d_out, int out_size, void* d_ws, size_t ws_size,
                              hipStream_t stream) {
    const float* x     = (const float*)d_in[0];
    const int*   ei    = (const int*)d_in[1];   // [2,E]
    const int*   batch = (const int*)d_in[3];
    const float* W0    = (const float*)d_in[4];
    const float* b0    = (const float*)d_in[5];
    const float* Wl    = (const float*)d_in[6];
    const float* bl    = (const float*)d_in[7];
    const float* Wr    = (const float*)d_in[8];
    const float* W1    = (const float*)d_in[9];
    const float* b1    = (const float*)d_in[10];
    float* out = (float*)d_out;

    char* ws = (char*)d_ws;
    size_t off = 0;
    auto alloc = [&](size_t bytes) -> void* {
        void* p = ws + off;
        off += (bytes + 255) & ~(size_t)255;
        return p;
    };
    float*          A      = (float*)alloc((size_t)NN * 64 * 4);          // h / r / h'
    __hip_bfloat16* G      = (__hip_bfloat16*)alloc((size_t)NN * 64 * 2); // g (bf16), NN rows
    // zero region starts EXACTLY at G's row NN (sentinel zero row), then cursor/pool/cntg
    size_t zstart = off;
    (void)alloc((size_t)MAXD * 2);                                        // G zero row (128 B)
    int*   cursor = (int*)alloc((size_t)NBUK * 4);
    float* pool   = (float*)alloc((size_t)NG * 64 * 4);
    float* cntg   = (float*)alloc((size_t)NG * 4);
    size_t zlen = off - zstart;
    int*          ell    = (int*)alloc((size_t)NBUK * 256 * MAXD * 4);    // padded ELL
    unsigned int* bucket = (unsigned int*)alloc((size_t)NBUK * BCAP * 4);
    int*          cnt    = (int*)alloc((size_t)NN * 4);                   // fully written

    const int* src = ei;
    const int* dst = ei + NE;

    hipMemsetAsync(ws + zstart, 0, zlen, stream);

    // phase-1 binning || input projection
    k_front<<<NBUK + GB, 512, 0, stream>>>(src, dst, cursor, bucket, x, W0, b0, A);
    // phase-2 ELL build || gemmLR layer 0
    k_mid<<<NBUK + MGB, 256, 0, stream>>>(bucket, cursor, cnt, ell, A, G,
                                          Wl, bl, Wr);
    k_gather<<<2048, 256, 0, stream>>>((const uint2*)G, A, cnt, ell);

    for (int l = 1; l < 3; ++l) {
        k_gemmLR<<<1024, 256, 0, stream>>>(A, G,
                                           Wl + (size_t)l * 64 * 64,
                                           bl + (size_t)l * 64,
                                           Wr + (size_t)l * 64 * 64);
        k_gather<<<2048, 256, 0, stream>>>((const uint2*)G, A, cnt, ell);
    }

    k_pool<<<256, 256, 0, stream>>>(batch, A, pool, cntg);
    k_out<<<128, 256, 0, stream>>>(pool, cntg, W1, b1, out);
}

// Round 13
// 519.762 us; speedup vs baseline: 1.2678x; 1.0029x over previous
//
#include <hip/hip_runtime.h>
#include <hip/hip_bf16.h>

#define NN 100000
#define NE 1600000
#define DIN 128
#define NG 512
#define MAXD 64
#define NBUK 391               // dst>>8 buckets (256 nodes each)
#define BCAP 5120              // mean 4092, +16 sigma
#define CHUNK ((NE + NBUK - 1) / NBUK)

// ============ fused: phase-1 binning (blocks 0..NBUK) || input GEMM (rest) ============
// input GEMM: float2-packed W0 in LDS, 4 nodes/wave, 8 fma chains (gemmLR_body shape)
#define GB 512
__global__ void __launch_bounds__(512) k_front(const int* __restrict__ src,
                                               const int* __restrict__ dst,
                                               int* __restrict__ cursor,
                                               unsigned int* __restrict__ bucket,
                                               const float* __restrict__ x,
                                               const float* __restrict__ W0,
                                               const float* __restrict__ b0,
                                               float* __restrict__ h) {
    __shared__ float2 sW2[64 * 64];          // 32 KB: {W0[2k2][j], W0[2k2+1][j]}
    __shared__ int lcnt[NBUK];
    __shared__ int lbase[NBUK];
    if (blockIdx.x < NBUK) {
        // ---- bin edges by dst>>8 via LDS histogram; 1 global atomic per (block,bucket) ----
        for (int i = threadIdx.x; i < NBUK; i += 512) lcnt[i] = 0;
        __syncthreads();
        int e0 = blockIdx.x * CHUNK;
        int e1 = min(e0 + CHUNK, NE);
        for (int e = e0 + (int)threadIdx.x; e < e1; e += 512)
            atomicAdd(&lcnt[dst[e] >> 8], 1);
        __syncthreads();
        for (int i = threadIdx.x; i < NBUK; i += 512) {
            int c = lcnt[i];
            lbase[i] = c ? atomicAdd(&cursor[i], c) : 0;
            lcnt[i] = 0;
        }
        __syncthreads();
        for (int e = e0 + (int)threadIdx.x; e < e1; e += 512) {
            int d = dst[e];
            int s = src[e];
            int bk = d >> 8;
            int pos = lbase[bk] + atomicAdd(&lcnt[bk], 1);
            if (pos < BCAP)
                bucket[(size_t)bk * BCAP + pos] = ((unsigned)s << 8) | (unsigned)(d & 255);
        }
    } else {
        // ---- input GEMM: h = relu(x @ W0 + b0), 4 nodes/wave ----
        for (int i = threadIdx.x; i < 64 * 64; i += 512) {
            int k2 = i >> 6, j = i & 63;
            sW2[i] = make_float2(W0[(2 * k2) * 64 + j], W0[(2 * k2 + 1) * 64 + j]);
        }
        __syncthreads();
        int lane = threadIdx.x & 63;
        int wv   = __builtin_amdgcn_readfirstlane(
                       (int)(((blockIdx.x - NBUK) * 512 + threadIdx.x) >> 6));
        int nw   = GB * 8;
        float bj = b0[lane];
        for (int q = wv; q < NN / 4; q += nw) {
            const float* xp = x + (size_t)(4 * q) * DIN;   // wave-uniform -> s_load
            float a0 = 0, a1 = 0, a2 = 0, a3 = 0;
            float c0 = 0, c1 = 0, c2 = 0, c3 = 0;
#pragma unroll 16
            for (int k2 = 0; k2 < 64; ++k2) {
                float2 w = sW2[k2 * 64 + lane];
                float s;
                s = xp[2 * k2];                a0 = fmaf(s, w.x, a0);
                s = xp[2 * k2 + 1];            c0 = fmaf(s, w.y, c0);
                s = xp[DIN + 2 * k2];          a1 = fmaf(s, w.x, a1);
                s = xp[DIN + 2 * k2 + 1];      c1 = fmaf(s, w.y, c1);
                s = xp[2 * DIN + 2 * k2];      a2 = fmaf(s, w.x, a2);
                s = xp[2 * DIN + 2 * k2 + 1];  c2 = fmaf(s, w.y, c2);
                s = xp[3 * DIN + 2 * k2];      a3 = fmaf(s, w.x, a3);
                s = xp[3 * DIN + 2 * k2 + 1];  c3 = fmaf(s, w.y, c3);
            }
            size_t base = (size_t)(4 * q) * 64 + lane;
            h[base]       = fmaxf(a0 + c0, 0.0f);
            h[base + 64]  = fmaxf(a1 + c1, 0.0f);
            h[base + 128] = fmaxf(a2 + c2, 0.0f);
            h[base + 192] = fmaxf(a3 + c3, 0.0f);
        }
    }
}

// ---- gemmLR body: g(bf16) = h@Wl ; r(fp32,in-place) = h@Wr + bl ----
__device__ __forceinline__ void gemmLR_body(float2* sW, int tid, int nblk, int bidx,
                                            float* __restrict__ h_r,
                                            __hip_bfloat16* __restrict__ g,
                                            const float* __restrict__ Wl,
                                            const float* __restrict__ bl,
                                            const float* __restrict__ Wr) {
    for (int i = tid; i < 64 * 64; i += 256)
        sW[i] = make_float2(Wl[i], Wr[i]);
    __syncthreads();
    int lane = tid & 63;
    float bj = bl[lane];
    int wv = __builtin_amdgcn_readfirstlane((int)((bidx * 256 + tid) >> 6));
    int nw = nblk * 4;
    for (int q = wv; q < NN / 4; q += nw) {
        const float* hp = h_r + (size_t)(4 * q) * 64;   // wave-uniform -> s_load
        float l0 = 0, l1 = 0, l2 = 0, l3 = 0;
        float r0 = 0, r1 = 0, r2 = 0, r3 = 0;
#pragma unroll 16
        for (int k = 0; k < 64; ++k) {
            float2 w = sW[k * 64 + lane];
            float s0 = hp[k], s1 = hp[64 + k], s2 = hp[128 + k], s3 = hp[192 + k];
            l0 = fmaf(s0, w.x, l0); r0 = fmaf(s0, w.y, r0);
            l1 = fmaf(s1, w.x, l1); r1 = fmaf(s1, w.y, r1);
            l2 = fmaf(s2, w.x, l2); r2 = fmaf(s2, w.y, r2);
            l3 = fmaf(s3, w.x, l3); r3 = fmaf(s3, w.y, r3);
        }
        size_t base = (size_t)(4 * q) * 64 + lane;
        g[base]       = __float2bfloat16(l0);  h_r[base]       = r0 + bj;
        g[base + 64]  = __float2bfloat16(l1);  h_r[base + 64]  = r1 + bj;
        g[base + 128] = __float2bfloat16(l2);  h_r[base + 128] = r2 + bj;
        g[base + 192] = __float2bfloat16(l3);  h_r[base + 192] = r3 + bj;
    }
}

// ============ fused: phase-2 ELL build (blocks 0..NBUK) || gemmLR layer 0 ============
#define MGB 1024
__global__ void __launch_bounds__(256) k_mid(const unsigned int* __restrict__ bucket,
                                             const int* __restrict__ cursor,
                                             int* __restrict__ cnt,
                                             int* __restrict__ ell,
                                             float* __restrict__ h_r,
                                             __hip_bfloat16* __restrict__ g,
                                             const float* __restrict__ Wl,
                                             const float* __restrict__ bl,
                                             const float* __restrict__ Wr) {
    __shared__ float2 sW[64 * 64];
    __shared__ int lc[256];
    if (blockIdx.x < NBUK) {
        lc[threadIdx.x] = 0;
        int b = blockIdx.x;
        int4* ep = (int4*)(ell + (((size_t)b << 8) * MAXD));
        for (int i = threadIdx.x; i < (256 * MAXD) / 4; i += 256)
            ep[i] = make_int4(NN, NN, NN, NN);          // sentinel -> zero row of G
        __syncthreads();
        int m = min(cursor[b], BCAP);
        const unsigned int* bp = bucket + (size_t)b * BCAP;
        for (int i = threadIdx.x; i < m; i += 256) {
            unsigned v = bp[i];
            int dlo = (int)(v & 255u);
            int s   = (int)(v >> 8);
            int p   = atomicAdd(&lc[dlo], 1);           // LDS atomic
            if (p < MAXD)
                ell[(((size_t)b << 8) + dlo) * MAXD + p] = s;
        }
        __syncthreads();
        int n = (b << 8) + (int)threadIdx.x;
        if (n < NN) cnt[n] = lc[threadIdx.x];
    } else {
        gemmLR_body(sW, threadIdx.x, MGB, blockIdx.x - NBUK, h_r, g, Wl, bl, Wr);
    }
}

// ============ standalone gemmLR (layers 1,2) ============
__global__ void __launch_bounds__(256) k_gemmLR(float* __restrict__ h_r,
                                                __hip_bfloat16* __restrict__ g,
                                                const float* __restrict__ Wl,
                                                const float* __restrict__ bl,
                                                const float* __restrict__ Wr) {
    __shared__ float2 sW[64 * 64];
    gemmLR_body(sW, threadIdx.x, gridDim.x, blockIdx.x, h_r, g, Wl, bl, Wr);
}

// ============ gather: 2 nodes/wave, 4 B/lane (bf16x2), sentinel-padded, 8-way ILP ====
// (round-10 variant: measured best)
__global__ void __launch_bounds__(256) k_gather(const unsigned int* __restrict__ g2,
                                                float* __restrict__ r_h,
                                                const int* __restrict__ cnt,
                                                const int* __restrict__ ell) {
    int lane = threadIdx.x & 63;
    int half = lane >> 5;
    int col  = lane & 31;
    int wv = __builtin_amdgcn_readfirstlane((int)((blockIdx.x * 256 + threadIdx.x) >> 6));
    int nw = (gridDim.x * 256) >> 6;
    for (int p = wv; p < NN / 2; p += nw) {
        int nA = 2 * p, nB = nA + 1;
        int dgA = cnt[nA], dgB = cnt[nB];               // wave-uniform scalar loads
        int myn  = half ? nB : nA;
        int mydg = half ? dgB : dgA;
        int maxd = min(max(dgA, dgB), MAXD);
        int iters = (maxd + 7) & ~7;                    // pad to 8; sentinels add 0
        int idx0 = ell[(size_t)myn * MAXD + col];
        int idx1 = NN;
        if (iters > 32) idx1 = ell[(size_t)myn * MAXD + 32 + col];
        float L0=0.f,L1=0.f,L2=0.f,L3=0.f,L4=0.f,L5=0.f,L6=0.f,L7=0.f;
        float H0=0.f,H1=0.f,H2=0.f,H3=0.f,H4=0.f,H5=0.f,H6=0.f,H7=0.f;
        int it0 = min(iters, 32);
        for (int j = 0; j < it0; j += 8) {
            int i0 = __shfl(idx0, half * 32 + j);
            int i1 = __shfl(idx0, half * 32 + j + 1);
            int i2 = __shfl(idx0, half * 32 + j + 2);
            int i3 = __shfl(idx0, half * 32 + j + 3);
            int i4 = __shfl(idx0, half * 32 + j + 4);
            int i5 = __shfl(idx0, half * 32 + j + 5);
            int i6 = __shfl(idx0, half * 32 + j + 6);
            int i7 = __shfl(idx0, half * 32 + j + 7);
            unsigned u0 = g2[(size_t)i0 * 32 + col];
            unsigned u1 = g2[(size_t)i1 * 32 + col];
            unsigned u2 = g2[(size_t)i2 * 32 + col];
            unsigned u3 = g2[(size_t)i3 * 32 + col];
            unsigned u4 = g2[(size_t)i4 * 32 + col];
            unsigned u5 = g2[(size_t)i5 * 32 + col];
            unsigned u6 = g2[(size_t)i6 * 32 + col];
            unsigned u7 = g2[(size_t)i7 * 32 + col];
            L0 += __uint_as_float(u0 << 16); H0 += __uint_as_float(u0 & 0xffff0000u);
            L1 += __uint_as_float(u1 << 16); H1 += __uint_as_float(u1 & 0xffff0000u);
            L2 += __uint_as_float(u2 << 16); H2 += __uint_as_float(u2 & 0xffff0000u);
            L3 += __uint_as_float(u3 << 16); H3 += __uint_as_float(u3 & 0xffff0000u);
            L4 += __uint_as_float(u4 << 16); H4 += __uint_as_float(u4 & 0xffff0000u);
            L5 += __uint_as_float(u5 << 16); H5 += __uint_as_float(u5 & 0xffff0000u);
            L6 += __uint_as_float(u6 << 16); H6 += __uint_as_float(u6 & 0xffff0000u);
            L7 += __uint_as_float(u7 << 16); H7 += __uint_as_float(u7 & 0xffff0000u);
        }
        for (int j = 0; j < iters - 32; j += 8) {
            int i0 = __shfl(idx1, half * 32 + j);
            int i1 = __shfl(idx1, half * 32 + j + 1);
            int i2 = __shfl(idx1, half * 32 + j + 2);
            int i3 = __shfl(idx1, half * 32 + j + 3);
            int i4 = __shfl(idx1, half * 32 + j + 4);
            int i5 = __shfl(idx1, half * 32 + j + 5);
            int i6 = __shfl(idx1, half * 32 + j + 6);
            int i7 = __shfl(idx1, half * 32 + j + 7);
            unsigned u0 = g2[(size_t)i0 * 32 + col];
            unsigned u1 = g2[(size_t)i1 * 32 + col];
            unsigned u2 = g2[(size_t)i2 * 32 + col];
            unsigned u3 = g2[(size_t)i3 * 32 + col];
            unsigned u4 = g2[(size_t)i4 * 32 + col];
            unsigned u5 = g2[(size_t)i5 * 32 + col];
            unsigned u6 = g2[(size_t)i6 * 32 + col];
            unsigned u7 = g2[(size_t)i7 * 32 + col];
            L0 += __uint_as_float(u0 << 16); H0 += __uint_as_float(u0 & 0xffff0000u);
            L1 += __uint_as_float(u1 << 16); H1 += __uint_as_float(u1 & 0xffff0000u);
            L2 += __uint_as_float(u2 << 16); H2 += __uint_as_float(u2 & 0xffff0000u);
            L3 += __uint_as_float(u3 << 16); H3 += __uint_as_float(u3 & 0xffff0000u);
            L4 += __uint_as_float(u4 << 16); H4 += __uint_as_float(u4 & 0xffff0000u);
            L5 += __uint_as_float(u5 << 16); H5 += __uint_as_float(u5 & 0xffff0000u);
            L6 += __uint_as_float(u6 << 16); H6 += __uint_as_float(u6 & 0xffff0000u);
            L7 += __uint_as_float(u7 << 16); H7 += __uint_as_float(u7 & 0xffff0000u);
        }
        float inv  = 1.0f / fmaxf((float)mydg, 1.0f);
        float sumL = ((L0 + L1) + (L2 + L3)) + ((L4 + L5) + (L6 + L7));
        float sumH = ((H0 + H1) + (H2 + H3)) + ((H4 + H5) + (H6 + H7));
        float2* rp = (float2*)r_h + (size_t)myn * 32 + col;
        float2 rv = *rp;
        rv.x = fmaxf(fmaf(sumL, inv, rv.x), 0.0f);
        rv.y = fmaxf(fmaf(sumH, inv, rv.y), 0.0f);
        *rp = rv;
    }
}

// ============ pooling (batch sorted -> run accumulate) ============
__global__ void __launch_bounds__(256) k_pool(const int* __restrict__ batch,
                                              const float* __restrict__ h,
                                              float* __restrict__ pool,
                                              float* __restrict__ cntg) {
    int lane = threadIdx.x & 63;
    int wid  = (blockIdx.x * 256 + threadIdx.x) >> 6;
    int nw   = (gridDim.x * 256) >> 6;
    int chunk = (NN + nw - 1) / nw;
    int n0 = wid * chunk;
    if (n0 >= NN) return;
    int n1 = min(n0 + chunk, NN);
    int cur = batch[n0];
    float acc = 0.0f, acc_c = 0.0f;
    for (int n = n0; n < n1; ++n) {
        int b = batch[n];
        if (b != cur) {
            atomicAdd(&pool[(size_t)cur * 64 + lane], acc);
            if (lane == 0) atomicAdd(&cntg[cur], acc_c);
            acc = 0.0f; acc_c = 0.0f; cur = b;
        }
        acc   += h[(size_t)n * 64 + lane];
        acc_c += 1.0f;
    }
    atomicAdd(&pool[(size_t)cur * 64 + lane], acc);
    if (lane == 0) atomicAdd(&cntg[cur], acc_c);
}

// ============ output GEMM ============
__global__ void __launch_bounds__(256) k_out(const float* __restrict__ pool,
                                             const float* __restrict__ cntg,
                                             const float* __restrict__ W1,
                                             const float* __restrict__ b1,
                                             float* __restrict__ out) {
    __shared__ float sW[64 * 64];
    for (int i = threadIdx.x; i < 64 * 64; i += 256) sW[i] = W1[i];
    __syncthreads();
    int lane = threadIdx.x & 63;
    int wid  = (blockIdx.x * 256 + threadIdx.x) >> 6;
    int nw   = (gridDim.x * 256) >> 6;
    for (int gidx = wid; gidx < NG; gidx += nw) {
        float ic = 1.0f / fmaxf(cntg[gidx], 1.0f);
        float acc = 0.0f;
#pragma unroll
        for (int k = 0; k < 64; ++k)
            acc = fmaf(pool[(size_t)gidx * 64 + k], sW[k * 64 + lane], acc);
        out[(size_t)gidx * 64 + lane] = fmaf(acc, ic, b1[lane]);
    }
}

extern "C" void kernel_launch(void* const* d_in, const int* in_sizes, int n_in,
                              void* d_out, int out_size, void* d_ws, size_t ws_size,
                              hipStream_t stream) {
    const float* x     = (const float*)d_in[0];
    const int*   ei    = (const int*)d_in[1];   // [2,E]
    const int*   batch = (const int*)d_in[3];
    const float* W0    = (const float*)d_in[4];
    const float* b0    = (const float*)d_in[5];
    const float* Wl    = (const float*)d_in[6];
    const float* bl    = (const float*)d_in[7];
    const float* Wr    = (const float*)d_in[8];
    const float* W1    = (const float*)d_in[9];
    const float* b1    = (const float*)d_in[10];
    float* out = (float*)d_out;

    char* ws = (char*)d_ws;
    size_t off = 0;
    auto alloc = [&](size_t bytes) -> void* {
        void* p = ws + off;
        off += (bytes + 255) & ~(size_t)255;
        return p;
    };
    float*          A      = (float*)alloc((size_t)NN * 64 * 4);          // h / r / h'
    __hip_bfloat16* G      = (__hip_bfloat16*)alloc((size_t)NN * 64 * 2); // g (bf16), NN rows
    // zero region starts EXACTLY at G's row NN (sentinel zero row), then cursor/pool/cntg
    size_t zstart = off;
    (void)alloc((size_t)MAXD * 2);                                        // G zero row (128 B)
    int*   cursor = (int*)alloc((size_t)NBUK * 4);
    float* pool   = (float*)alloc((size_t)NG * 64 * 4);
    float* cntg   = (float*)alloc((size_t)NG * 4);
    size_t zlen = off - zstart;
    int*          ell    = (int*)alloc((size_t)NBUK * 256 * MAXD * 4);    // padded ELL
    unsigned int* bucket = (unsigned int*)alloc((size_t)NBUK * BCAP * 4);
    int*          cnt    = (int*)alloc((size_t)NN * 4);                   // fully written

    const int* src = ei;
    const int* dst = ei + NE;

    hipMemsetAsync(ws + zstart, 0, zlen, stream);

    // phase-1 binning || input projection
    k_front<<<NBUK + GB, 512, 0, stream>>>(src, dst, cursor, bucket, x, W0, b0, A);
    // phase-2 ELL build || gemmLR layer 0
    k_mid<<<NBUK + MGB, 256, 0, stream>>>(bucket, cursor, cnt, ell, A, G,
                                          Wl, bl, Wr);
    k_gather<<<4096, 256, 0, stream>>>((const unsigned int*)G, A, cnt, ell);

    for (int l = 1; l < 3; ++l) {
        k_gemmLR<<<1024, 256, 0, stream>>>(A, G,
                                           Wl + (size_t)l * 64 * 64,
                                           bl + (size_t)l * 64,
                                           Wr + (size_t)l * 64 * 64);
        k_gather<<<4096, 256, 0, stream>>>((const unsigned int*)G, A, cnt, ell);
    }

    k_pool<<<256, 256, 0, stream>>>(batch, A, pool, cntg);
    k_out<<<128, 256, 0, stream>>>(pool, cntg, W1, b1, out);
}